// Round 17
// baseline (240.267 us; speedup 1.0000x reference)
//
#include <hip/hip_runtime.h>
#include <hip/hip_bf16.h>

#define N_NODES 30000
#define N_EDGES 1000000
#define N_GRAPHS 256
#define HEADS 8
#define DHEAD 16
#define HIDDEN 128
#define LAYERS 3
#define KPN 17
#define KPE 16
#define NEG_SLOPE 0.2f
#define BN_EPS 1e-5f
#define ET (N_EDGES + N_NODES)
#define NBIN 235           /* ceil(30000/128) */
#define BINW 128           /* nodes per bin */
#define BINCAP 6016        /* mean load ~4266, max ~4600 */
#define CHUNK 4096
#define NB_EDGE 245        /* ceil(1M/4096) */
#define NBG 1876           /* 938 row-blocks x 2 col-halves */

typedef __attribute__((ext_vector_type(8))) short bf16x8;
typedef __attribute__((ext_vector_type(4))) float f32x4;

__device__ __forceinline__ unsigned bf16_rne(float f) {
    unsigned u = __float_as_uint(f);
    return (u + 0x7fffu + ((u >> 16) & 1u)) >> 16;
}
__device__ __forceinline__ float bf16_lo(unsigned w) { return __uint_as_float(w << 16); }
__device__ __forceinline__ float bf16_hi(unsigned w) { return __uint_as_float(w & 0xffff0000u); }

// ---------------- pre: zero bcnt + gptr + weight convert + kp projection table ----------------
__global__ __launch_bounds__(256) void k_pre(const int* __restrict__ batch,
                                             int* __restrict__ bcnt,
                                             int* __restrict__ gptr,
                                             int* __restrict__ ptr,
                                             const float* __restrict__ w_l,
                                             const float* __restrict__ w_r,
                                             const float* __restrict__ kp_emb,
                                             const float* __restrict__ w_in,
                                             const float* __restrict__ b_in,
                                             unsigned short* __restrict__ wT,
                                             float* __restrict__ kpp) {
    int bid = blockIdx.x, t = threadIdx.x;
    if (bid == 0) {
        if (t < NBIN) bcnt[t] = 0;
        for (int g = t; g <= N_GRAPHS; g += 256) {
            if (g == N_GRAPHS) { gptr[g] = N_NODES; }
            else {
                int lo = 0, hi = N_NODES;
                while (lo < hi) {
                    int mid = (lo + hi) >> 1;
                    if (batch[mid] < g) lo = mid + 1; else hi = mid;
                }
                gptr[g] = lo;
            }
        }
        if (t == 0) ptr[N_NODES] = ET;
    } else if (bid <= 384) {
        int idx = (bid - 1) * 256 + t;
        if (idx < LAYERS * 256 * 128) {
            int l = idx / (256 * 128);
            int rem = idx - l * 256 * 128;
            int c = rem >> 7;
            int k = rem & 127;
            float v = (c < 128) ? w_l[(size_t)l * 16384 + k * 128 + c]
                                : w_r[(size_t)l * 16384 + k * 128 + (c - 128)];
            wT[idx] = (unsigned short)bf16_rne(v);
        }
    } else {
        int idx = (bid - 385) * 256 + t;
        if (idx < KPN * 128) {
            int p = idx >> 7, c = idx & 127;
            float acc = b_in[c];
#pragma unroll
            for (int k = 0; k < KPE; ++k)
                acc += kp_emb[p * KPE + k] * w_in[(3 + k) * 128 + c];
            kpp[idx] = acc;
        }
    }
}

// ---------------- MFMA dual GEMM; FUSED adds inproj + concurrent CSR pass A ----------------
template<bool FUSED>
__global__ __launch_bounds__(256) void k_gemmT(const float* __restrict__ x,
                                               const float* __restrict__ kpp,
                                               const float* __restrict__ w_in,
                                               unsigned short* __restrict__ hb_out,
                                               const unsigned short* __restrict__ hb,
                                               const unsigned short* __restrict__ wT,
                                               unsigned short* __restrict__ xlb,
                                               unsigned short* __restrict__ xrb,
                                               const int* __restrict__ ei,
                                               int* __restrict__ bcnt,
                                               unsigned* __restrict__ bdata) {
    __shared__ unsigned short st[32][132];
    __shared__ unsigned short hsA[FUSED ? 32 : 1][136];
    __shared__ int lcnt[FUSED ? NBIN : 1];
    __shared__ int lbase[FUSED ? NBIN : 1];
    int tid = threadIdx.x;

    if (FUSED && blockIdx.x < NB_EDGE) {
        int base = blockIdx.x * CHUNK;
        int n = N_EDGES - base; if (n > CHUNK) n = CHUNK;
        for (int i = tid; i < NBIN; i += 256) lcnt[i] = 0;
        __syncthreads();
        for (int t = tid; t < n; t += 256) {
            int d = ei[N_EDGES + base + t];
            atomicAdd(&lcnt[d >> 7], 1);
        }
        __syncthreads();
        for (int i = tid; i < NBIN; i += 256) {
            int c = lcnt[i];
            lbase[i] = c ? atomicAdd(&bcnt[i], c) : 0;
            lcnt[i] = 0;
        }
        __syncthreads();
        for (int t = tid; t < n; t += 256) {
            int s = ei[base + t];
            int d = ei[N_EDGES + base + t];
            int b = d >> 7;
            int pos = lbase[b] + atomicAdd(&lcnt[b], 1);
            bdata[(size_t)b * BINCAP + pos] = (unsigned)s | ((unsigned)(d & 127) << 15);
        }
        return;
    }

    int gbid = FUSED ? (blockIdx.x - NB_EDGE) : blockIdx.x;
    int half = gbid & 1;
    int brow = (gbid >> 1) * 32;
    int wave = tid >> 6, lane = tid & 63;
    int lr = lane & 15, lk = lane >> 4;

    if (FUSED) {
        int r = tid >> 3, c16 = (tid & 7) * 16;
        int gr = brow + r;
        int gc = gr < N_NODES ? gr : 0;
        float xv0 = x[gc * 3], xv1 = x[gc * 3 + 1], xv2 = x[gc * 3 + 2];
        const float* kprow = kpp + (gc % KPN) * 128;
        float res[16];
#pragma unroll
        for (int q = 0; q < 16; ++q) {
            int c = c16 + q;
            res[q] = kprow[c] + xv0 * w_in[c] + xv1 * w_in[128 + c] + xv2 * w_in[256 + c];
        }
        unsigned short pk16[16];
#pragma unroll
        for (int q = 0; q < 16; ++q) pk16[q] = (unsigned short)bf16_rne(res[q]);
        if (gr < N_NODES && half == 0) {
            *(uint4*)(hb_out + (size_t)gr * 128 + c16)     = *(uint4*)&pk16[0];
            *(uint4*)(hb_out + (size_t)gr * 128 + c16 + 8) = *(uint4*)&pk16[8];
        }
#pragma unroll
        for (int q = 0; q < 16; ++q) hsA[r][c16 + q] = pk16[q];
        __syncthreads();
    }

    int ar0c = brow + lr;      if (ar0c >= N_NODES) ar0c = N_NODES - 1;
    int ar1c = brow + 16 + lr; if (ar1c >= N_NODES) ar1c = N_NODES - 1;
    int c0l = wave * 32 + lr;
    const unsigned short* wb = wT + (size_t)(half * 128 + c0l) * 128 + lk * 8;

    f32x4 acc[2][2];
#pragma unroll
    for (int m = 0; m < 2; ++m)
#pragma unroll
        for (int n = 0; n < 2; ++n) acc[m][n] = (f32x4){0.f, 0.f, 0.f, 0.f};

#pragma unroll
    for (int ks = 0; ks < 4; ++ks) {
        bf16x8 a0, a1;
        if (FUSED) {
            a0 = *(const bf16x8*)&hsA[lr][lk * 8 + ks * 32];
            a1 = *(const bf16x8*)&hsA[16 + lr][lk * 8 + ks * 32];
        } else {
            a0 = *(const bf16x8*)(hb + (size_t)ar0c * 128 + lk * 8 + ks * 32);
            a1 = *(const bf16x8*)(hb + (size_t)ar1c * 128 + lk * 8 + ks * 32);
        }
#pragma unroll
        for (int nt = 0; nt < 2; ++nt) {
            bf16x8 b = *(const bf16x8*)(wb + nt * 16 * 128 + ks * 32);
            acc[0][nt] = __builtin_amdgcn_mfma_f32_16x16x32_bf16(a0, b, acc[0][nt], 0, 0, 0);
            acc[1][nt] = __builtin_amdgcn_mfma_f32_16x16x32_bf16(a1, b, acc[1][nt], 0, 0, 0);
        }
    }

    int r0 = lk * 4;
#pragma unroll
    for (int mt = 0; mt < 2; ++mt)
#pragma unroll
        for (int nt = 0; nt < 2; ++nt)
#pragma unroll
            for (int j = 0; j < 4; ++j)
                st[mt * 16 + r0 + j][c0l + nt * 16] = (unsigned short)bf16_rne(acc[mt][nt][j]);
    __syncthreads();

    int rr = tid >> 3, seg = tid & 7;
    int grow = brow + rr;
    if (grow < N_NODES) {
        unsigned short* dst = (half == 0 ? xlb : xrb) + (size_t)grow * 128 + seg * 16;
        *(uint4*)(dst)     = *(uint4*)&st[rr][seg * 16];
        *(uint4*)(dst + 8) = *(uint4*)&st[rr][seg * 16 + 8];
    }
}

// ---------------- CSR pass B: fully LDS-staged per-bin placement ----------------
__global__ __launch_bounds__(256) void k_place2(const int* __restrict__ bcnt,
                                                const unsigned* __restrict__ bdata,
                                                int* __restrict__ ptr,
                                                unsigned short* __restrict__ csr_src) {
    __shared__ int vsc[256];
    __shared__ unsigned ldata[BINCAP];
    __shared__ unsigned short lcsr[BINCAP + BINW];
    __shared__ int hist[BINW], pre[BINW], nodestart[BINW], lofs[BINW];
    __shared__ int bbase_sh;
    int b = blockIdx.x, tid = threadIdx.x;
    int n = bcnt[b];
    int nNodes = N_NODES - b * BINW; if (nNodes > BINW) nNodes = BINW;

    for (int t = tid; t < n; t += 256) ldata[t] = bdata[(size_t)b * BINCAP + t];

    int c = 0;
    if (tid < NBIN) {
        int nodes = N_NODES - tid * BINW; if (nodes > BINW) nodes = BINW;
        c = bcnt[tid] + nodes;
    }
    vsc[tid] = c;
    if (tid < BINW) hist[tid] = (tid < nNodes) ? 1 : 0;   // self loop seed
    __syncthreads();
    for (int off = 1; off < 256; off <<= 1) {
        int x = (tid >= off) ? vsc[tid - off] : 0;
        __syncthreads();
        vsc[tid] += x;
        __syncthreads();
    }
    if (tid == 0) bbase_sh = (b == 0) ? 0 : vsc[b - 1];

    for (int t = tid; t < n; t += 256)
        atomicAdd(&hist[(ldata[t] >> 15) & 127], 1);
    __syncthreads();
    if (tid < BINW) pre[tid] = hist[tid];
    __syncthreads();
    for (int off = 1; off < BINW; off <<= 1) {
        int x = (tid >= off && tid < BINW) ? pre[tid - off] : 0;
        __syncthreads();
        if (tid < BINW) pre[tid] += x;
        __syncthreads();
    }
    if (tid < BINW) {
        int ns = pre[tid] - hist[tid];
        nodestart[tid] = ns;
        if (tid < nNodes) {
            int node = b * BINW + tid;
            ptr[node] = bbase_sh + ns;
            lcsr[ns] = (unsigned short)node;
        }
        lofs[tid] = 1;
    }
    __syncthreads();
    for (int t = tid; t < n; t += 256) {
        unsigned e = ldata[t];
        int dl = (e >> 15) & 127;
        int pos = nodestart[dl] + atomicAdd(&lofs[dl], 1);
        lcsr[pos] = (unsigned short)(e & 0x7fffu);
    }
    __syncthreads();
    int tot = n + nNodes;
    for (int t = tid; t < tot; t += 256) csr_src[bbase_sh + t] = lcsr[t];
}

// ---------------- GATv2 per-node kernel ----------------
// 1 wave per node; 4 edges/iter (16 lanes each, 8 dims/lane, dwordx4 loads);
// leaky(z)=0.6z+0.4|z| packed fma streams; bf16 residual RMW
__global__ __launch_bounds__(256) void k_gat(const uint4* __restrict__ xlb4,
                                             const uint4* __restrict__ xrb4,
                                             const int* __restrict__ ptr,
                                             const unsigned short* __restrict__ csr_src,
                                             const float* __restrict__ att_l,
                                             const float* __restrict__ bias_l,
                                             const float* __restrict__ gamma_l,
                                             const float* __restrict__ beta_l,
                                             const float* __restrict__ mean_l,
                                             const float* __restrict__ var_l,
                                             unsigned* __restrict__ hb32) {
    int wid = (blockIdx.x * 256 + threadIdx.x) >> 6;
    int lane = threadIdx.x & 63;
    if (wid >= N_NODES) return;
    int i = wid;
    int e4 = lane >> 4;
    int l16 = lane & 15;
    int d0 = 8 * l16;

    uint4 xw = xrb4[(size_t)i * 16 + l16];
    float2 xra = make_float2(bf16_lo(xw.x), bf16_hi(xw.x));
    float2 xrb_ = make_float2(bf16_lo(xw.y), bf16_hi(xw.y));
    float2 xrc = make_float2(bf16_lo(xw.z), bf16_hi(xw.z));
    float2 xrd = make_float2(bf16_lo(xw.w), bf16_hi(xw.w));
    const float L2E = 1.44269504089f;
    float4 avA = *(const float4*)(att_l + d0);
    float4 avB = *(const float4*)(att_l + d0 + 4);
    float2 a6a = make_float2(avA.x * (0.6f * L2E), avA.y * (0.6f * L2E));
    float2 a6b = make_float2(avA.z * (0.6f * L2E), avA.w * (0.6f * L2E));
    float2 a6c = make_float2(avB.x * (0.6f * L2E), avB.y * (0.6f * L2E));
    float2 a6d = make_float2(avB.z * (0.6f * L2E), avB.w * (0.6f * L2E));
    float2 a4a = make_float2(avA.x * (0.4f * L2E), avA.y * (0.4f * L2E));
    float2 a4b = make_float2(avA.z * (0.4f * L2E), avA.w * (0.4f * L2E));
    float2 a4c = make_float2(avB.x * (0.4f * L2E), avB.y * (0.4f * L2E));
    float2 a4d = make_float2(avB.z * (0.4f * L2E), avB.w * (0.4f * L2E));
    int e0 = ptr[i], e1 = ptr[i + 1];

    float denom = 0.f;
    float2 acA = make_float2(0.f, 0.f), acB = make_float2(0.f, 0.f);
    float2 acC = make_float2(0.f, 0.f), acD = make_float2(0.f, 0.f);

#define LDQ(KQ, WREG, VREG) { \
    int eo = 4 * (KQ) + e4; \
    int sr = __shfl(sv, eo); \
    VREG = eo < cnt; \
    int rw = VREG ? sr : 0; \
    WREG = xlb4[(size_t)rw * 16 + l16]; \
}
#define PROCQ(WREG, VREG) { \
    float2 va = make_float2(bf16_lo(WREG.x), bf16_hi(WREG.x)); \
    float2 vb = make_float2(bf16_lo(WREG.y), bf16_hi(WREG.y)); \
    float2 vc = make_float2(bf16_lo(WREG.z), bf16_hi(WREG.z)); \
    float2 vd = make_float2(bf16_lo(WREG.w), bf16_hi(WREG.w)); \
    float2 za, zb, zc, zd; \
    za.x = va.x + xra.x;  za.y = va.y + xra.y; \
    zb.x = vb.x + xrb_.x; zb.y = vb.y + xrb_.y; \
    zc.x = vc.x + xrc.x;  zc.y = vc.y + xrc.y; \
    zd.x = vd.x + xrd.x;  zd.y = vd.y + xrd.y; \
    float2 p6, p4; \
    p6.x = za.x * a6a.x;  p6.y = za.y * a6a.y; \
    p6.x = fmaf(zb.x, a6b.x, p6.x); p6.y = fmaf(zb.y, a6b.y, p6.y); \
    p6.x = fmaf(zc.x, a6c.x, p6.x); p6.y = fmaf(zc.y, a6c.y, p6.y); \
    p6.x = fmaf(zd.x, a6d.x, p6.x); p6.y = fmaf(zd.y, a6d.y, p6.y); \
    p4.x = fabsf(za.x) * a4a.x;  p4.y = fabsf(za.y) * a4a.y; \
    p4.x = fmaf(fabsf(zb.x), a4b.x, p4.x); p4.y = fmaf(fabsf(zb.y), a4b.y, p4.y); \
    p4.x = fmaf(fabsf(zc.x), a4c.x, p4.x); p4.y = fmaf(fabsf(zc.y), a4c.y, p4.y); \
    p4.x = fmaf(fabsf(zd.x), a4d.x, p4.x); p4.y = fmaf(fabsf(zd.y), a4d.y, p4.y); \
    float p = (p6.x + p4.x) + (p6.y + p4.y); \
    p += __shfl_xor(p, 1); \
    float ex = VREG ? exp2f(p) : 0.f; \
    denom += ex; \
    acA.x = fmaf(ex, va.x, acA.x); acA.y = fmaf(ex, va.y, acA.y); \
    acB.x = fmaf(ex, vb.x, acB.x); acB.y = fmaf(ex, vb.y, acB.y); \
    acC.x = fmaf(ex, vc.x, acC.x); acC.y = fmaf(ex, vc.y, acC.y); \
    acD.x = fmaf(ex, vd.x, acD.x); acD.y = fmaf(ex, vd.y, acD.y); \
}

    for (int base = e0; base < e1; base += 64) {
        int idx = base + lane;
        int sv = (idx < e1) ? (int)csr_src[idx] : 0;
        int cnt = e1 - base; if (cnt > 64) cnt = 64;
        int nq = (cnt + 3) >> 2;

        uint4 w0, w1; bool b0 = false, b1 = false;
        LDQ(0, w0, b0);
        if (1 < nq) LDQ(1, w1, b1);
        int k = 0;
        for (; k + 2 < nq; k += 2) {
            uint4 n0, n1; bool c0v, c1v;
            LDQ(k + 2, n0, c0v);
            LDQ(k + 3, n1, c1v);
            PROCQ(w0, b0); PROCQ(w1, b1);
            w0 = n0; b0 = c0v; w1 = n1; b1 = c1v;
        }
        PROCQ(w0, b0);
        if (k + 1 < nq) PROCQ(w1, b1);
    }
#undef LDQ
#undef PROCQ

    denom += __shfl_xor(denom, 16); denom += __shfl_xor(denom, 32);
    acA.x += __shfl_xor(acA.x, 16); acA.x += __shfl_xor(acA.x, 32);
    acA.y += __shfl_xor(acA.y, 16); acA.y += __shfl_xor(acA.y, 32);
    acB.x += __shfl_xor(acB.x, 16); acB.x += __shfl_xor(acB.x, 32);
    acB.y += __shfl_xor(acB.y, 16); acB.y += __shfl_xor(acB.y, 32);
    acC.x += __shfl_xor(acC.x, 16); acC.x += __shfl_xor(acC.x, 32);
    acC.y += __shfl_xor(acC.y, 16); acC.y += __shfl_xor(acC.y, 32);
    acD.x += __shfl_xor(acD.x, 16); acD.x += __shfl_xor(acD.x, 32);
    acD.y += __shfl_xor(acD.y, 16); acD.y += __shfl_xor(acD.y, 32);

    if (e4 == 0) {
        float inv = 1.f / denom;
        float4 biaA = *(const float4*)(bias_l + d0),  biaB = *(const float4*)(bias_l + d0 + 4);
        float4 gamA = *(const float4*)(gamma_l + d0), gamB = *(const float4*)(gamma_l + d0 + 4);
        float4 betA = *(const float4*)(beta_l + d0),  betB = *(const float4*)(beta_l + d0 + 4);
        float4 meaA = *(const float4*)(mean_l + d0),  meaB = *(const float4*)(mean_l + d0 + 4);
        float4 varA = *(const float4*)(var_l + d0),   varB = *(const float4*)(var_l + d0 + 4);
        float o0 = fmaxf(acA.x * inv + biaA.x, 0.f);
        float o1 = fmaxf(acA.y * inv + biaA.y, 0.f);
        float o2 = fmaxf(acB.x * inv + biaA.z, 0.f);
        float o3 = fmaxf(acB.y * inv + biaA.w, 0.f);
        float o4 = fmaxf(acC.x * inv + biaB.x, 0.f);
        float o5 = fmaxf(acC.y * inv + biaB.y, 0.f);
        float o6 = fmaxf(acD.x * inv + biaB.z, 0.f);
        float o7 = fmaxf(acD.y * inv + biaB.w, 0.f);
        o0 = (o0 - meaA.x) * (gamA.x * rsqrtf(varA.x + BN_EPS)) + betA.x;
        o1 = (o1 - meaA.y) * (gamA.y * rsqrtf(varA.y + BN_EPS)) + betA.y;
        o2 = (o2 - meaA.z) * (gamA.z * rsqrtf(varA.z + BN_EPS)) + betA.z;
        o3 = (o3 - meaA.w) * (gamA.w * rsqrtf(varA.w + BN_EPS)) + betA.w;
        o4 = (o4 - meaB.x) * (gamB.x * rsqrtf(varB.x + BN_EPS)) + betB.x;
        o5 = (o5 - meaB.y) * (gamB.y * rsqrtf(varB.y + BN_EPS)) + betB.y;
        o6 = (o6 - meaB.z) * (gamB.z * rsqrtf(varB.z + BN_EPS)) + betB.z;
        o7 = (o7 - meaB.w) * (gamB.w * rsqrtf(varB.w + BN_EPS)) + betB.w;
        // bf16 residual RMW: row = 64 dwords, this lane's dwords = [4*l16, 4*l16+3]
        unsigned* hp = hb32 + ((size_t)i << 6) + (l16 << 2);
        uint4 hw = *(const uint4*)hp;
        float h0 = bf16_lo(hw.x) + o0, h1 = bf16_hi(hw.x) + o1;
        float h2 = bf16_lo(hw.y) + o2, h3 = bf16_hi(hw.y) + o3;
        float h4 = bf16_lo(hw.z) + o4, h5 = bf16_hi(hw.z) + o5;
        float h6 = bf16_lo(hw.w) + o6, h7 = bf16_hi(hw.w) + o7;
        uint4 pk;
        pk.x = bf16_rne(h0) | (bf16_rne(h1) << 16);
        pk.y = bf16_rne(h2) | (bf16_rne(h3) << 16);
        pk.z = bf16_rne(h4) | (bf16_rne(h5) << 16);
        pk.w = bf16_rne(h6) | (bf16_rne(h7) << 16);
        *(uint4*)hp = pk;
    }
}

// ---------------- fused pooling + classifier MLP (1 block per graph; bf16 h) ----------------
__global__ __launch_bounds__(256) void k_poolmlp(const unsigned short* __restrict__ hb,
                                                 const int* __restrict__ gptr,
                                                 const float* __restrict__ w1, const float* __restrict__ b1,
                                                 const float* __restrict__ w2, const float* __restrict__ b2,
                                                 const float* __restrict__ w3, const float* __restrict__ b3,
                                                 float* __restrict__ out) {
    __shared__ float red[256];
    __shared__ float g[128], t1[256], t2[128];
    int b = blockIdx.x, t = threadIdx.x;
    int c = t & 127, half = t >> 7;
    int lo = gptr[b], hi = gptr[b + 1];
    float s = 0.f;
    for (int i = lo + half; i < hi; i += 2)
        s += __uint_as_float((unsigned)hb[(size_t)i * 128 + c] << 16);
    red[t] = s;
    __syncthreads();
    if (half == 0) {
        float cntf = fmaxf((float)(hi - lo), 1.0f);
        g[c] = (red[c] + red[c + 128]) / cntf;
    }
    __syncthreads();
    {
        float acc = b1[t];
        for (int k = 0; k < 128; ++k) acc += g[k] * w1[k * 256 + t];
        t1[t] = acc > 0.f ? acc : expm1f(acc);
    }
    __syncthreads();
    if (t < 128) {
        float acc = b2[t];
        for (int k = 0; k < 256; ++k) acc += t1[k] * w2[k * 128 + t];
        t2[t] = acc > 0.f ? acc : expm1f(acc);
    }
    __syncthreads();
    if (t < 2) {
        float acc = b3[t];
        for (int k = 0; k < 128; ++k) acc += t2[k] * w3[k * 2 + t];
        out[b * 2 + t] = acc;
    }
}

// ---------------- launch ----------------
extern "C" void kernel_launch(void* const* d_in, const int* in_sizes, int n_in,
                              void* d_out, int out_size, void* d_ws, size_t ws_size,
                              hipStream_t stream) {
    const float* x        = (const float*)d_in[0];
    const int*   ei       = (const int*)d_in[1];
    const int*   batch    = (const int*)d_in[2];
    const float* kp_emb   = (const float*)d_in[3];
    const float* w_in     = (const float*)d_in[4];
    const float* b_in     = (const float*)d_in[5];
    const float* w_l      = (const float*)d_in[6];
    const float* w_r      = (const float*)d_in[7];
    const float* att      = (const float*)d_in[8];
    const float* conv_b   = (const float*)d_in[9];
    const float* bn_gamma = (const float*)d_in[10];
    const float* bn_beta  = (const float*)d_in[11];
    const float* bn_mean  = (const float*)d_in[12];
    const float* bn_var   = (const float*)d_in[13];
    const float* w1 = (const float*)d_in[14];
    const float* b1 = (const float*)d_in[15];
    const float* w2 = (const float*)d_in[16];
    const float* b2 = (const float*)d_in[17];
    const float* w3 = (const float*)d_in[18];
    const float* b3 = (const float*)d_in[19];
    float* out = (float*)d_out;

    char* ws = (char*)d_ws;
    const size_t OFF_HB   = 0;                                    // bf16 h (residual stream)
    const size_t OFF_XL   = OFF_HB   + 7680000;
    const size_t OFF_XR   = OFF_XL   + 7680000;
    const size_t OFF_WT   = OFF_XR   + 7680000;                   // bf16 wT [3][256][128]
    const size_t OFF_PTR  = OFF_WT   + 196608;
    const size_t OFF_BCNT = OFF_PTR  + 120320;
    const size_t OFF_SRC  = OFF_BCNT + 1024;                      // ushort csr [ET]
    const size_t OFF_GPTR = OFF_SRC  + 2060032;
    const size_t OFF_BD   = OFF_GPTR + 1088;                      // bdata [NBIN][BINCAP]
    const size_t OFF_KPP  = OFF_BD   + (size_t)NBIN * BINCAP * 4; // f32 kpp [17][128]

    unsigned short* hb     = (unsigned short*)(ws + OFF_HB);
    unsigned short* xlb    = (unsigned short*)(ws + OFF_XL);
    unsigned short* xrb    = (unsigned short*)(ws + OFF_XR);
    unsigned short* wT     = (unsigned short*)(ws + OFF_WT);
    int*            ptr    = (int*)(ws + OFF_PTR);
    int*            bcnt   = (int*)(ws + OFF_BCNT);
    unsigned short* csrsrc = (unsigned short*)(ws + OFF_SRC);
    int*            gptr   = (int*)(ws + OFF_GPTR);
    unsigned*       bdata  = (unsigned*)(ws + OFF_BD);
    float*          kpp    = (float*)(ws + OFF_KPP);

    k_pre<<<385 + (KPN * 128 + 255) / 256, 256, 0, stream>>>(
        batch, bcnt, gptr, ptr, w_l, w_r, kp_emb, w_in, b_in, wT, kpp);

    k_gemmT<true><<<NB_EDGE + NBG, 256, 0, stream>>>(
        x, kpp, w_in, hb, hb, wT, xlb, xrb, ei, bcnt, bdata);

    k_place2<<<NBIN, 256, 0, stream>>>(bcnt, bdata, ptr, csrsrc);

    for (int l = 0; l < LAYERS; ++l) {
        if (l > 0) {
            k_gemmT<false><<<NBG, 256, 0, stream>>>(
                x, kpp, w_in, hb, hb, wT + (size_t)l * 256 * 128, xlb, xrb,
                ei, bcnt, bdata);
        }
        k_gat<<<(N_NODES + 3) / 4, 256, 0, stream>>>(
            (const uint4*)xlb, (const uint4*)xrb, ptr, csrsrc,
            att + (size_t)l * 128, conv_b + (size_t)l * 128,
            bn_gamma + (size_t)l * 128, bn_beta + (size_t)l * 128,
            bn_mean + (size_t)l * 128, bn_var + (size_t)l * 128,
            (unsigned*)hb);
    }

    k_poolmlp<<<N_GRAPHS, 256, 0, stream>>>(hb, gptr, w1, b1, w2, b2, w3, b3, out);
}

// Round 18
// 235.848 us; speedup vs baseline: 1.0187x; 1.0187x over previous
//
#include <hip/hip_runtime.h>
#include <hip/hip_bf16.h>

#define N_NODES 30000
#define N_EDGES 1000000
#define N_GRAPHS 256
#define HEADS 8
#define DHEAD 16
#define HIDDEN 128
#define LAYERS 3
#define KPN 17
#define KPE 16
#define NEG_SLOPE 0.2f
#define BN_EPS 1e-5f
#define ET (N_EDGES + N_NODES)
#define NBIN 235           /* ceil(30000/128) */
#define BINW 128           /* nodes per bin */
#define BINCAP 6016        /* mean load ~4266, max ~4600 */
#define CHUNK 4096
#define NB_EDGE 245        /* ceil(1M/4096) */
#define NBG 1876           /* 938 row-blocks x 2 col-halves */
#define PRE_MISC 1
#define PRE_WCONV 384
#define PRE_KPP 9          /* ceil(17*128/256) */

typedef __attribute__((ext_vector_type(8))) short bf16x8;
typedef __attribute__((ext_vector_type(4))) float f32x4;

__device__ __forceinline__ unsigned bf16_rne(float f) {
    unsigned u = __float_as_uint(f);
    return (u + 0x7fffu + ((u >> 16) & 1u)) >> 16;
}
__device__ __forceinline__ float bf16_lo(unsigned w) { return __uint_as_float(w << 16); }
__device__ __forceinline__ float bf16_hi(unsigned w) { return __uint_as_float(w & 0xffff0000u); }

// ---------------- pre: gptr + weight convert + kpp table + CSR pass A (binning) ----------------
__global__ __launch_bounds__(256) void k_pre(const int* __restrict__ batch,
                                             int* __restrict__ bcnt,
                                             int* __restrict__ gptr,
                                             int* __restrict__ ptr,
                                             const float* __restrict__ w_l,
                                             const float* __restrict__ w_r,
                                             const float* __restrict__ kp_emb,
                                             const float* __restrict__ w_in,
                                             const float* __restrict__ b_in,
                                             unsigned short* __restrict__ wT,
                                             float* __restrict__ kpp,
                                             const int* __restrict__ ei,
                                             unsigned* __restrict__ bdata) {
    __shared__ int lcnt[NBIN];
    __shared__ int lbase[NBIN];
    int bid = blockIdx.x, t = threadIdx.x;
    if (bid == 0) {
        for (int g = t; g <= N_GRAPHS; g += 256) {
            if (g == N_GRAPHS) { gptr[g] = N_NODES; }
            else {
                int lo = 0, hi = N_NODES;
                while (lo < hi) {
                    int mid = (lo + hi) >> 1;
                    if (batch[mid] < g) lo = mid + 1; else hi = mid;
                }
                gptr[g] = lo;
            }
        }
        if (t == 0) ptr[N_NODES] = ET;
    } else if (bid <= PRE_WCONV) {
        int idx = (bid - 1) * 256 + t;
        if (idx < LAYERS * 256 * 128) {
            int l = idx / (256 * 128);
            int rem = idx - l * 256 * 128;
            int c = rem >> 7;
            int k = rem & 127;
            float v = (c < 128) ? w_l[(size_t)l * 16384 + k * 128 + c]
                                : w_r[(size_t)l * 16384 + k * 128 + (c - 128)];
            wT[idx] = (unsigned short)bf16_rne(v);
        }
    } else if (bid <= PRE_WCONV + PRE_KPP) {
        int idx = (bid - PRE_WCONV - 1) * 256 + t;
        if (idx < KPN * 128) {
            int p = idx >> 7, c = idx & 127;
            float acc = b_in[c];
#pragma unroll
            for (int k = 0; k < KPE; ++k)
                acc += kp_emb[p * KPE + k] * w_in[(3 + k) * 128 + c];
            kpp[idx] = acc;
        }
    } else {
        // CSR pass A: LDS-aggregated binning of one 4096-edge chunk
        int base = (bid - PRE_WCONV - PRE_KPP - 1) * CHUNK;
        int n = N_EDGES - base; if (n > CHUNK) n = CHUNK;
        for (int i = t; i < NBIN; i += 256) lcnt[i] = 0;
        __syncthreads();
        for (int q = t; q < n; q += 256) {
            int d = ei[N_EDGES + base + q];
            atomicAdd(&lcnt[d >> 7], 1);
        }
        __syncthreads();
        for (int i = t; i < NBIN; i += 256) {
            int c = lcnt[i];
            lbase[i] = c ? atomicAdd(&bcnt[i], c) : 0;
            lcnt[i] = 0;
        }
        __syncthreads();
        for (int q = t; q < n; q += 256) {
            int s = ei[base + q];
            int d = ei[N_EDGES + base + q];
            int b = d >> 7;
            int pos = lbase[b] + atomicAdd(&lcnt[b], 1);
            bdata[(size_t)b * BINCAP + pos] = (unsigned)s | ((unsigned)(d & 127) << 15);
        }
    }
}

// ---------------- MFMA dual GEMM; FUSED adds inproj + concurrent CSR pass B (place2) ----------------
// FUSED grid: [0,NBIN) = place2; [NBIN, NBIN+NBG) = inproj+gemm.  non-FUSED grid: [0,NBG).
template<bool FUSED>
__global__ __launch_bounds__(256) void k_gemmT(const float* __restrict__ x,
                                               const float* __restrict__ kpp,
                                               const float* __restrict__ w_in,
                                               unsigned short* __restrict__ hb_out,
                                               const unsigned short* __restrict__ hb,
                                               const unsigned short* __restrict__ wT,
                                               unsigned short* __restrict__ xlb,
                                               unsigned short* __restrict__ xrb,
                                               const int* __restrict__ bcnt,
                                               const unsigned* __restrict__ bdata,
                                               int* __restrict__ ptr,
                                               unsigned short* __restrict__ csr_src) {
    __shared__ char smem[17408];
    unsigned short (*st)[136]  = (unsigned short(*)[136])smem;
    unsigned short (*hsA)[136] = (unsigned short(*)[136])(smem + 8704);
    int tid = threadIdx.x;

    if (FUSED && blockIdx.x < NBIN) {
        // ---- CSR pass B: per-bin placement (bdata read twice from global; csr staged in LDS) ----
        int* vsc        = (int*)smem;                              // 1024
        int* hist       = (int*)(smem + 1024);                     // 512
        int* pre        = (int*)(smem + 1536);                     // 512
        int* nodestart  = (int*)(smem + 2048);                     // 512
        int* lofs       = (int*)(smem + 2560);                     // 512
        int* bbase_sh   = (int*)(smem + 3072);                     // 4
        unsigned short* lcsr = (unsigned short*)(smem + 3088);     // 6144 ushorts = 12288

        int b = blockIdx.x;
        int n = bcnt[b];
        int nNodes = N_NODES - b * BINW; if (nNodes > BINW) nNodes = BINW;

        int c = 0;
        if (tid < NBIN) {
            int nodes = N_NODES - tid * BINW; if (nodes > BINW) nodes = BINW;
            c = bcnt[tid] + nodes;
        }
        vsc[tid] = c;
        if (tid < BINW) hist[tid] = (tid < nNodes) ? 1 : 0;   // self loop seed
        __syncthreads();
        for (int off = 1; off < 256; off <<= 1) {
            int xv = (tid >= off) ? vsc[tid - off] : 0;
            __syncthreads();
            vsc[tid] += xv;
            __syncthreads();
        }
        if (tid == 0) *bbase_sh = (b == 0) ? 0 : vsc[b - 1];

        for (int q = tid; q < n; q += 256)
            atomicAdd(&hist[(bdata[(size_t)b * BINCAP + q] >> 15) & 127], 1);
        __syncthreads();
        if (tid < BINW) pre[tid] = hist[tid];
        __syncthreads();
        for (int off = 1; off < BINW; off <<= 1) {
            int xv = (tid >= off && tid < BINW) ? pre[tid - off] : 0;
            __syncthreads();
            if (tid < BINW) pre[tid] += xv;
            __syncthreads();
        }
        if (tid < BINW) {
            int ns = pre[tid] - hist[tid];
            nodestart[tid] = ns;
            if (tid < nNodes) {
                int node = b * BINW + tid;
                ptr[node] = *bbase_sh + ns;
                lcsr[ns] = (unsigned short)node;   // self loop
            }
            lofs[tid] = 1;
        }
        __syncthreads();
        for (int q = tid; q < n; q += 256) {
            unsigned e = bdata[(size_t)b * BINCAP + q];
            int dl = (e >> 15) & 127;
            int pos = nodestart[dl] + atomicAdd(&lofs[dl], 1);
            lcsr[pos] = (unsigned short)(e & 0x7fffu);
        }
        __syncthreads();
        int tot = n + nNodes;
        int bb = *bbase_sh;
        for (int q = tid; q < tot; q += 256) csr_src[bb + q] = lcsr[q];
        return;
    }

    int gbid = FUSED ? (blockIdx.x - NBIN) : blockIdx.x;
    int half = gbid & 1;
    int brow = (gbid >> 1) * 32;
    int wave = tid >> 6, lane = tid & 63;
    int lr = lane & 15, lk = lane >> 4;

    if (FUSED) {
        // input projection: 3 FMAs + kpp add per element -> hb (global) + hsA (LDS)
        int r = tid >> 3, c16 = (tid & 7) * 16;
        int gr = brow + r;
        int gc = gr < N_NODES ? gr : 0;
        float xv0 = x[gc * 3], xv1 = x[gc * 3 + 1], xv2 = x[gc * 3 + 2];
        const float* kprow = kpp + (gc % KPN) * 128;
        float res[16];
#pragma unroll
        for (int q = 0; q < 16; ++q) {
            int c = c16 + q;
            res[q] = kprow[c] + xv0 * w_in[c] + xv1 * w_in[128 + c] + xv2 * w_in[256 + c];
        }
        unsigned short pk16[16];
#pragma unroll
        for (int q = 0; q < 16; ++q) pk16[q] = (unsigned short)bf16_rne(res[q]);
        if (gr < N_NODES && half == 0) {
            *(uint4*)(hb_out + (size_t)gr * 128 + c16)     = *(uint4*)&pk16[0];
            *(uint4*)(hb_out + (size_t)gr * 128 + c16 + 8) = *(uint4*)&pk16[8];
        }
#pragma unroll
        for (int q = 0; q < 16; ++q) hsA[r][c16 + q] = pk16[q];
    } else {
        // cooperative A-tile staging from hb (coalesced, once per block)
        int r = tid >> 3, seg = tid & 7;
        int gr = brow + r; if (gr >= N_NODES) gr = N_NODES - 1;
        const unsigned short* srcp = hb + (size_t)gr * 128 + seg * 16;
        *(uint4*)&hsA[r][seg * 16]     = *(const uint4*)srcp;
        *(uint4*)&hsA[r][seg * 16 + 8] = *(const uint4*)(srcp + 8);
    }
    __syncthreads();

    int c0l = wave * 32 + lr;
    const unsigned short* wb = wT + (size_t)(half * 128 + c0l) * 128 + lk * 8;

    f32x4 acc[2][2];
#pragma unroll
    for (int m = 0; m < 2; ++m)
#pragma unroll
        for (int n = 0; n < 2; ++n) acc[m][n] = (f32x4){0.f, 0.f, 0.f, 0.f};

#pragma unroll
    for (int ks = 0; ks < 4; ++ks) {
        bf16x8 a0 = *(const bf16x8*)&hsA[lr][lk * 8 + ks * 32];
        bf16x8 a1 = *(const bf16x8*)&hsA[16 + lr][lk * 8 + ks * 32];
#pragma unroll
        for (int nt = 0; nt < 2; ++nt) {
            bf16x8 b = *(const bf16x8*)(wb + nt * 16 * 128 + ks * 32);
            acc[0][nt] = __builtin_amdgcn_mfma_f32_16x16x32_bf16(a0, b, acc[0][nt], 0, 0, 0);
            acc[1][nt] = __builtin_amdgcn_mfma_f32_16x16x32_bf16(a1, b, acc[1][nt], 0, 0, 0);
        }
    }

    int r0 = lk * 4;
#pragma unroll
    for (int mt = 0; mt < 2; ++mt)
#pragma unroll
        for (int nt = 0; nt < 2; ++nt)
#pragma unroll
            for (int j = 0; j < 4; ++j)
                st[mt * 16 + r0 + j][c0l + nt * 16] = (unsigned short)bf16_rne(acc[mt][nt][j]);
    __syncthreads();

    int rr = tid >> 3, seg = tid & 7;
    int grow = brow + rr;
    if (grow < N_NODES) {
        unsigned short* dst = (half == 0 ? xlb : xrb) + (size_t)grow * 128 + seg * 16;
        *(uint4*)(dst)     = *(uint4*)&st[rr][seg * 16];
        *(uint4*)(dst + 8) = *(uint4*)&st[rr][seg * 16 + 8];
    }
}

// ---------------- GATv2 per-node kernel (2 edges/iter, 32 lanes each; bf16 residual) ----------------
__global__ __launch_bounds__(256) void k_gat(const unsigned* __restrict__ xlb,
                                             const unsigned* __restrict__ xrb,
                                             const int* __restrict__ ptr,
                                             const unsigned short* __restrict__ csr_src,
                                             const float* __restrict__ att_l,
                                             const float* __restrict__ bias_l,
                                             const float* __restrict__ gamma_l,
                                             const float* __restrict__ beta_l,
                                             const float* __restrict__ mean_l,
                                             const float* __restrict__ var_l,
                                             unsigned* __restrict__ hb32) {
    int wid = (blockIdx.x * 256 + threadIdx.x) >> 6;
    int lane = threadIdx.x & 63;
    if (wid >= N_NODES) return;
    int i = wid;
    int grp = lane >> 5;
    int l32 = lane & 31;
    int d0 = 4 * l32;

    uint2 xw = *(const uint2*)(xrb + ((size_t)i << 6) + (l32 << 1));
    float xr0 = bf16_lo(xw.x), xr1 = bf16_hi(xw.x);
    float xr2 = bf16_lo(xw.y), xr3 = bf16_hi(xw.y);
    const float L2E = 1.44269504089f;
    float4 av = *(const float4*)(att_l + d0);
    av.x *= L2E; av.y *= L2E; av.z *= L2E; av.w *= L2E;
    int e0 = ptr[i], e1 = ptr[i + 1];

    float denom = 0.f, acc0 = 0.f, acc1 = 0.f, acc2 = 0.f, acc3 = 0.f;

#define LDP(KP, WREG, VREG) { \
    int eo = 2 * (KP) + grp; \
    int sr = __shfl(sv, eo); \
    VREG = eo < cnt; \
    int rw = VREG ? sr : 0; \
    WREG = *(const uint2*)(xlb + ((size_t)rw << 6) + (l32 << 1)); \
}
#define PROCP(WREG, VREG) { \
    float v0 = bf16_lo(WREG.x), v1 = bf16_hi(WREG.x); \
    float v2 = bf16_lo(WREG.y), v3 = bf16_hi(WREG.y); \
    float z0 = v0 + xr0, z1 = v1 + xr1, z2 = v2 + xr2, z3 = v3 + xr3; \
    z0 = fmaxf(z0, NEG_SLOPE * z0); \
    z1 = fmaxf(z1, NEG_SLOPE * z1); \
    z2 = fmaxf(z2, NEG_SLOPE * z2); \
    z3 = fmaxf(z3, NEG_SLOPE * z3); \
    float p = z0 * av.x + z1 * av.y + z2 * av.z + z3 * av.w; \
    p += __shfl_xor(p, 1); \
    p += __shfl_xor(p, 2); \
    float ex = VREG ? exp2f(p) : 0.f; \
    denom += ex; \
    acc0 += ex * v0; acc1 += ex * v1; acc2 += ex * v2; acc3 += ex * v3; \
}

    for (int base = e0; base < e1; base += 64) {
        int idx = base + lane;
        int sv = (idx < e1) ? (int)csr_src[idx] : 0;
        int cnt = e1 - base; if (cnt > 64) cnt = 64;
        int np = (cnt + 1) >> 1;

        uint2 w0, w1; bool b0 = false, b1 = false;
        LDP(0, w0, b0);
        if (1 < np) LDP(1, w1, b1);
        int k = 0;
        for (; k + 2 < np; k += 2) {
            uint2 n0, n1; bool c0v, c1v;
            LDP(k + 2, n0, c0v);
            LDP(k + 3, n1, c1v);
            PROCP(w0, b0); PROCP(w1, b1);
            w0 = n0; b0 = c0v; w1 = n1; b1 = c1v;
        }
        PROCP(w0, b0);
        if (k + 1 < np) PROCP(w1, b1);
    }
#undef LDP
#undef PROCP

    denom += __shfl_xor(denom, 32);
    acc0 += __shfl_xor(acc0, 32);
    acc1 += __shfl_xor(acc1, 32);
    acc2 += __shfl_xor(acc2, 32);
    acc3 += __shfl_xor(acc3, 32);

    if (grp == 0) {
        float inv = 1.f / denom;
        float4 bia = *(const float4*)(bias_l + d0);
        float4 gam = *(const float4*)(gamma_l + d0);
        float4 bet = *(const float4*)(beta_l + d0);
        float4 mea = *(const float4*)(mean_l + d0);
        float4 var = *(const float4*)(var_l + d0);
        float o0 = fmaxf(acc0 * inv + bia.x, 0.f);
        float o1 = fmaxf(acc1 * inv + bia.y, 0.f);
        float o2 = fmaxf(acc2 * inv + bia.z, 0.f);
        float o3 = fmaxf(acc3 * inv + bia.w, 0.f);
        o0 = (o0 - mea.x) * (gam.x * rsqrtf(var.x + BN_EPS)) + bet.x;
        o1 = (o1 - mea.y) * (gam.y * rsqrtf(var.y + BN_EPS)) + bet.y;
        o2 = (o2 - mea.z) * (gam.z * rsqrtf(var.z + BN_EPS)) + bet.z;
        o3 = (o3 - mea.w) * (gam.w * rsqrtf(var.w + BN_EPS)) + bet.w;
        unsigned* hp = hb32 + ((size_t)i << 6) + (l32 << 1);
        uint2 hw = *(const uint2*)hp;
        float h0 = bf16_lo(hw.x), h1 = bf16_hi(hw.x);
        float h2 = bf16_lo(hw.y), h3 = bf16_hi(hw.y);
        h0 += o0; h1 += o1; h2 += o2; h3 += o3;
        uint2 pk;
        pk.x = bf16_rne(h0) | (bf16_rne(h1) << 16);
        pk.y = bf16_rne(h2) | (bf16_rne(h3) << 16);
        *(uint2*)hp = pk;
    }
}

// ---------------- fused pooling + classifier MLP (1 block per graph; bf16 h) ----------------
__global__ __launch_bounds__(256) void k_poolmlp(const unsigned short* __restrict__ hb,
                                                 const int* __restrict__ gptr,
                                                 const float* __restrict__ w1, const float* __restrict__ b1,
                                                 const float* __restrict__ w2, const float* __restrict__ b2,
                                                 const float* __restrict__ w3, const float* __restrict__ b3,
                                                 float* __restrict__ out) {
    __shared__ float red[256];
    __shared__ float g[128], t1[256], t2[128];
    int b = blockIdx.x, t = threadIdx.x;
    int c = t & 127, half = t >> 7;
    int lo = gptr[b], hi = gptr[b + 1];
    float s = 0.f;
    for (int i = lo + half; i < hi; i += 2)
        s += __uint_as_float((unsigned)hb[(size_t)i * 128 + c] << 16);
    red[t] = s;
    __syncthreads();
    if (half == 0) {
        float cntf = fmaxf((float)(hi - lo), 1.0f);
        g[c] = (red[c] + red[c + 128]) / cntf;
    }
    __syncthreads();
    {
        float acc = b1[t];
        for (int k = 0; k < 128; ++k) acc += g[k] * w1[k * 256 + t];
        t1[t] = acc > 0.f ? acc : expm1f(acc);
    }
    __syncthreads();
    if (t < 128) {
        float acc = b2[t];
        for (int k = 0; k < 256; ++k) acc += t1[k] * w2[k * 128 + t];
        t2[t] = acc > 0.f ? acc : expm1f(acc);
    }
    __syncthreads();
    if (t < 2) {
        float acc = b3[t];
        for (int k = 0; k < 128; ++k) acc += t2[k] * w3[k * 2 + t];
        out[b * 2 + t] = acc;
    }
}

// ---------------- launch ----------------
extern "C" void kernel_launch(void* const* d_in, const int* in_sizes, int n_in,
                              void* d_out, int out_size, void* d_ws, size_t ws_size,
                              hipStream_t stream) {
    const float* x        = (const float*)d_in[0];
    const int*   ei       = (const int*)d_in[1];
    const int*   batch    = (const int*)d_in[2];
    const float* kp_emb   = (const float*)d_in[3];
    const float* w_in     = (const float*)d_in[4];
    const float* b_in     = (const float*)d_in[5];
    const float* w_l      = (const float*)d_in[6];
    const float* w_r      = (const float*)d_in[7];
    const float* att      = (const float*)d_in[8];
    const float* conv_b   = (const float*)d_in[9];
    const float* bn_gamma = (const float*)d_in[10];
    const float* bn_beta  = (const float*)d_in[11];
    const float* bn_mean  = (const float*)d_in[12];
    const float* bn_var   = (const float*)d_in[13];
    const float* w1 = (const float*)d_in[14];
    const float* b1 = (const float*)d_in[15];
    const float* w2 = (const float*)d_in[16];
    const float* b2 = (const float*)d_in[17];
    const float* w3 = (const float*)d_in[18];
    const float* b3 = (const float*)d_in[19];
    float* out = (float*)d_out;

    char* ws = (char*)d_ws;
    const size_t OFF_HB   = 0;                                    // bf16 h (residual stream)
    const size_t OFF_XL   = OFF_HB   + 7680000;
    const size_t OFF_XR   = OFF_XL   + 7680000;
    const size_t OFF_WT   = OFF_XR   + 7680000;                   // bf16 wT [3][256][128]
    const size_t OFF_PTR  = OFF_WT   + 196608;
    const size_t OFF_BCNT = OFF_PTR  + 120320;
    const size_t OFF_SRC  = OFF_BCNT + 1024;                      // ushort csr [ET]
    const size_t OFF_GPTR = OFF_SRC  + 2060032;
    const size_t OFF_BD   = OFF_GPTR + 1088;                      // bdata [NBIN][BINCAP]
    const size_t OFF_KPP  = OFF_BD   + (size_t)NBIN * BINCAP * 4; // f32 kpp [17][128]

    unsigned short* hb     = (unsigned short*)(ws + OFF_HB);
    unsigned short* xlb    = (unsigned short*)(ws + OFF_XL);
    unsigned short* xrb    = (unsigned short*)(ws + OFF_XR);
    unsigned short* wT     = (unsigned short*)(ws + OFF_WT);
    int*            ptr    = (int*)(ws + OFF_PTR);
    int*            bcnt   = (int*)(ws + OFF_BCNT);
    unsigned short* csrsrc = (unsigned short*)(ws + OFF_SRC);
    int*            gptr   = (int*)(ws + OFF_GPTR);
    unsigned*       bdata  = (unsigned*)(ws + OFF_BD);
    float*          kpp    = (float*)(ws + OFF_KPP);

    hipMemsetAsync(bcnt, 0, NBIN * 4, stream);

    // pre: misc + wconv + kpp + CSR binning (pass A)
    k_pre<<<PRE_MISC + PRE_WCONV + PRE_KPP + NB_EDGE, 256, 0, stream>>>(
        batch, bcnt, gptr, ptr, w_l, w_r, kp_emb, w_in, b_in, wT, kpp, ei, bdata);

    // fused: CSR pass B (place2) runs concurrently with inproj+gemm0
    k_gemmT<true><<<NBIN + NBG, 256, 0, stream>>>(
        x, kpp, w_in, hb, hb, wT, xlb, xrb, bcnt, bdata, ptr, csrsrc);

    for (int l = 0; l < LAYERS; ++l) {
        if (l > 0) {
            k_gemmT<false><<<NBG, 256, 0, stream>>>(
                x, kpp, w_in, hb, hb, wT + (size_t)l * 256 * 128, xlb, xrb,
                bcnt, bdata, ptr, csrsrc);
        }
        k_gat<<<(N_NODES + 3) / 4, 256, 0, stream>>>(
            (const unsigned*)xlb, (const unsigned*)xrb, ptr, csrsrc,
            att + (size_t)l * 128, conv_b + (size_t)l * 128,
            bn_gamma + (size_t)l * 128, bn_beta + (size_t)l * 128,
            bn_mean + (size_t)l * 128, bn_var + (size_t)l * 128,
            (unsigned*)hb);
    }

    k_poolmlp<<<N_GRAPHS, 256, 0, stream>>>(hb, gptr, w1, b1, w2, b2, w3, b3, out);
}